// Round 10
// baseline (215.585 us; speedup 1.0000x reference)
//
#include <hip/hip_runtime.h>
#include <hip/hip_bf16.h>
#include <stdint.h>

#define D_MODEL 1024
#define NH 16
#define HD 64
#define SEQ 2048
#define BATCH 2
#define ROWS (BATCH * SEQ)   // 4096
#define KDIM 1024
#define NQKV 3072

typedef unsigned short u16;
typedef short bf16x8 __attribute__((ext_vector_type(8)));   // 8 bf16 in 4 VGPRs
typedef short bf16x4 __attribute__((ext_vector_type(4)));   // 4 bf16 in 2 VGPRs
typedef float f32x4 __attribute__((ext_vector_type(4)));

__device__ __forceinline__ u16 f2bf(float f) {
  union { float f; unsigned u; } x; x.f = f;
  unsigned r = x.u + 0x7fff + ((x.u >> 16) & 1);   // RNE
  return (u16)(r >> 16);
}
__device__ __forceinline__ float bf2f(u16 h) {
  union { unsigned u; float f; } x; x.u = ((unsigned)h) << 16;
  return x.f;
}

// packed RNE f32x2 -> bf16x2 (v_cvt_pk_bf16_f32 on gfx950)
__device__ __forceinline__ bf16x4 pack4(float a, float b, float c, float d) {
  union { __hip_bfloat162 h2[2]; bf16x4 v; } u;
  u.h2[0] = __float22bfloat162_rn(make_float2(a, b));
  u.h2[1] = __float22bfloat162_rn(make_float2(c, d));
  return u.v;
}
__device__ __forceinline__ ushort4 packu4(float a, float b, float c, float d) {
  union { __hip_bfloat162 h2[2]; ushort4 v; } u;
  u.h2[0] = __float22bfloat162_rn(make_float2(a, b));
  u.h2[1] = __float22bfloat162_rn(make_float2(c, d));
  return u.v;
}

#ifndef HAVE_MFMA16_1K
#if defined(__has_builtin)
#if __has_builtin(__builtin_amdgcn_mfma_f32_16x16x16bf16_1k)
#define HAVE_MFMA16_1K 1
#endif
#endif
#endif
__device__ __forceinline__ f32x4 mfma16(bf16x4 a, bf16x4 b, f32x4 c) {
#ifdef HAVE_MFMA16_1K
  return __builtin_amdgcn_mfma_f32_16x16x16bf16_1k(a, b, c, 0, 0, 0);
#else
  bf16x8 a8 = {a[0], a[1], a[2], a[3], 0, 0, 0, 0};
  bf16x8 b8 = {b[0], b[1], b[2], b[3], 0, 0, 0, 0};
  return __builtin_amdgcn_mfma_f32_16x16x32_bf16(a8, b8, c, 0, 0, 0);
#endif
}

// async global->LDS, 16B/lane. LDS dst is wave-uniform base + lane*16;
// global SOURCE address is per-lane arbitrary (16B contiguous) -> swizzle there.
__device__ __forceinline__ void gload16(const u16* g, u16* l) {
  __builtin_amdgcn_global_load_lds(
      (const __attribute__((address_space(1))) unsigned int*)g,
      (__attribute__((address_space(3))) unsigned int*)l, 16, 0, 0);
}

// rank -> (q-tile, part) tables for flash split-K. part: 0/1 = key-half, 2 = full.
// Descending workload order so round-robin dispatch balances CUs (~34 iters/CU).
__device__ const int c_rt[23] = {8,15,15,7,14,14,13,13,6,12,12,11,11,5,10,10,9,9,4,3,2,1,0};
__device__ const int c_rp[23] = {2,0, 1, 2,0, 1, 0, 1, 2,0, 1, 0, 1, 2,0, 1, 0,1,2,2,2,2,2};

// ---- fused prep: query cvt, weight transposes, rope table [s][f] ----
__global__ void prep_kernel(const float* __restrict__ query, u16* __restrict__ q_bf,
                            const float* __restrict__ W_qkv, u16* __restrict__ wt_qkv,
                            const float* __restrict__ W_out, u16* __restrict__ wt_out,
                            float2* __restrict__ rope_tab) {
  __shared__ float tile[32][33];
  const int blk = blockIdx.x, tid = threadIdx.x;
  if (blk < 4096) {                       // query fp32 -> bf16
    int i = blk * 256 + tid;
    float4 v = ((const float4*)query)[i];
    ushort4 o;
    o.x = f2bf(v.x); o.y = f2bf(v.y); o.z = f2bf(v.z); o.w = f2bf(v.w);
    ((ushort4*)q_bf)[i] = o;
  } else if (blk < 8192) {                // W transpose+convert (32x32 tiles)
    const float* W; u16* Wt; int N, t;
    if (blk < 7168) { W = W_qkv; Wt = wt_qkv; N = NQKV; t = blk - 4096; }
    else            { W = W_out; Wt = wt_out; N = D_MODEL; t = blk - 7168; }
    int nb = N / 32;
    int c0 = (t % nb) * 32, r0 = (t / nb) * 32;
    int tx = tid & 31, ty = tid >> 5;
    for (int i = ty; i < 32; i += 8)
      tile[i][tx] = W[(size_t)(r0 + i) * N + c0 + tx];
    __syncthreads();
    for (int i = ty; i < 32; i += 8)
      Wt[(size_t)(c0 + i) * KDIM + r0 + tx] = f2bf(tile[tx][i]);
  } else {                                // rope table: tab[s*32+f] = (cos, sin)
    int i = (blk - 8192) * 256 + tid;
    int s = i >> 5, f = i & 31;
    float inv = __expf(-(float)f * 0.28782313662425572f);  // ln(1e4)/32
    float ang = (float)s * inv;
    rope_tab[i] = make_float2(cosf(ang), sinf(ang));
  }
}

// ---------------- QKV GEMM (R7 version, measured 50.3 us) ----------------
// XOR-swizzled LDS staging (0 conflicts). Epilogue: RoPE via table, in-wave LDS
// transpose for q/k -> coalesced 16B stores; v^T packed 8B stores. q pre-scaled kS.
__global__ __launch_bounds__(256) void qkv_gemm_kernel(
    const u16* __restrict__ A, const u16* __restrict__ Bt, const float* __restrict__ bias,
    const float2* __restrict__ rope_tab,
    u16* __restrict__ qb, u16* __restrict__ kb, u16* __restrict__ vtb) {
  __shared__ u16 smem[16384];            // As | Bs, reused by epilogue transpose
  u16* As = smem;
  u16* Bs = smem + 8192;
  const int tid = threadIdx.x;
  const int lane = tid & 63, wave = tid >> 6;
  const int wr = (wave >> 1) << 6, wc = (wave & 1) << 6;
  const int lrow = lane & 15, quad = lane >> 4;
  const int sw = lrow & 7;
  const int rowA0 = blockIdx.y * 128, rowB0 = blockIdx.x * 128;

  f32x4 acc[4][4] = {};

  for (int k0 = 0; k0 < KDIM; k0 += 64) {
    __syncthreads();
#pragma unroll
    for (int it = 0; it < 4; ++it) {
      int flat = it * 256 + tid;
      int r = flat >> 3, cs = ((flat & 7) ^ (r & 7)) << 3;   // source swizzle
      gload16(A + (size_t)(rowA0 + r) * KDIM + k0 + cs, As + flat * 8);
      gload16(Bt + (size_t)(rowB0 + r) * KDIM + k0 + cs, Bs + flat * 8);
    }
    __syncthreads();
#pragma unroll
    for (int kk = 0; kk < 64; kk += 32) {
      const int ch = ((kk >> 3) + quad) ^ sw;    // swizzled chunk, uniform per lane
      bf16x8 af[4], bfr[4];
#pragma unroll
      for (int mi = 0; mi < 4; ++mi)
        af[mi] = *(const bf16x8*)(As + (wr + mi * 16 + lrow) * 64 + (ch << 3));
#pragma unroll
      for (int ni = 0; ni < 4; ++ni)
        bfr[ni] = *(const bf16x8*)(Bs + (wc + ni * 16 + lrow) * 64 + (ch << 3));
#pragma unroll
      for (int mi = 0; mi < 4; ++mi)
#pragma unroll
        for (int ni = 0; ni < 4; ++ni)
          acc[mi][ni] = __builtin_amdgcn_mfma_f32_16x16x32_bf16(af[mi], bfr[ni], acc[mi][ni], 0, 0, 0);
    }
  }
  __syncthreads();   // all waves done with As/Bs before epilogue reuses smem

  const int col0 = rowB0 + wc;           // 64-aligned -> one head-slab per wave
  const int which = col0 >> 10;          // 0=q 1=k 2=v (wave-uniform)
  const int h = (col0 & 1023) >> 6;
  const int b = rowA0 >> 11;
  const int sbase = (rowA0 & 2047) + wr;

#pragma unroll
  for (int ni = 0; ni < 4; ++ni) {
    float bv = bias[col0 + ni * 16 + lrow];
#pragma unroll
    for (int mi = 0; mi < 4; ++mi)
#pragma unroll
      for (int r = 0; r < 4; ++r) acc[mi][ni][r] += bv;
  }

  if (which < 2) {
    // RoPE via table; q additionally pre-scaled by kS = log2(e)/sqrt(HD)
    const float qs = (which == 0) ? 0.18033688011112042f : 1.0f;
#pragma unroll
    for (int p = 0; p < 2; ++p) {
#pragma unroll
      for (int mi = 0; mi < 4; ++mi)
#pragma unroll
        for (int r = 0; r < 4; ++r) {
          int sg = sbase + mi * 16 + quad * 4 + r;
          float2 cs = rope_tab[sg * 32 + p * 16 + lrow];
          float x1 = acc[mi][p][r], x2 = acc[mi][p + 2][r];
          acc[mi][p][r]     = (x1 * cs.x - x2 * cs.y) * qs;
          acc[mi][p + 2][r] = (x2 * cs.x + x1 * cs.y) * qs;
        }
    }
    // in-wave LDS transpose (xor-swizzled cols), then coalesced 16B stores
    u16* myt = smem + wave * 4096;       // 64 x 64 bf16 slab
#pragma unroll
    for (int ni = 0; ni < 4; ++ni) {
      int hd = ni * 16 + lrow;
#pragma unroll
      for (int mi = 0; mi < 4; ++mi)
#pragma unroll
        for (int r = 0; r < 4; ++r) {
          int sl = mi * 16 + quad * 4 + r;
          int pos = ((((hd >> 3) ^ (sl & 7)) << 3)) | (hd & 7);
          myt[sl * 64 + pos] = f2bf(acc[mi][ni][r]);
        }
    }
    u16* dst = ((which == 0) ? qb : kb) + ((size_t)(b * NH + h) * SEQ + sbase) * HD;
    const int a = lane >> 3, pb = lane & 7;
#pragma unroll
    for (int it = 0; it < 8; ++it) {
      int sl = it * 8 + a;
      bf16x8 v = *(const bf16x8*)(myt + sl * 64 + (pb << 3));
      *(bf16x8*)(dst + sl * 64 + ((pb ^ a) << 3)) = v;   // undo swizzle -> plain
    }
  } else {
    // V^T: C-layout r-quad = 4 consecutive s at fixed hd -> packed 8B stores
    u16* dst = vtb + (size_t)(b * NH + h) * HD * SEQ;
#pragma unroll
    for (int ni = 0; ni < 4; ++ni) {
      int hd = ni * 16 + lrow;
#pragma unroll
      for (int mi = 0; mi < 4; ++mi) {
        ushort4 pk = packu4(acc[mi][ni][0], acc[mi][ni][1], acc[mi][ni][2], acc[mi][ni][3]);
        *(ushort4*)(dst + (size_t)hd * SEQ + sbase + mi * 16 + quad * 4) = pk;
      }
    }
  }
}

// ---------------- causal flash attention v8: split-K + l-via-MFMA ----------------
// 736 blocks: q-tiles t=0..8 whole (rank table), t=9..15 split into two key-halves
// whose partials (bf16 O, fp32 l) are exactly summable thanks to the fixed exp2
// offset. 64-key dbuf tiles -> 32 KB LDS -> ~3 blocks/CU resident (launch_bounds
// pins VGPR<=128 for 4 waves/SIMD). Wave owns 32 q (2 groups); K/V fragments read
// once feed both. Denominator accumulated on the MFMA pipe via an all-ones A
// fragment (every C row = sum_k P[k][q]) — no VALU adds, no final shuffles.
__global__ __launch_bounds__(256, 4) void flash_kernel(
    const u16* __restrict__ qb, const u16* __restrict__ kb,
    const u16* __restrict__ vtb, u16* __restrict__ attnb,
    u16* __restrict__ opart, float* __restrict__ lpart) {
  __shared__ u16 Ks[2][64 * 64];       // 16 KB (key-major, chunk^row swizzle)
  __shared__ u16 Vts[2][64 * 64];      // 16 KB (hd-major,  chunk^row swizzle)

  const int tid = threadIdx.x, lane = tid & 63, wave = tid >> 6;
  const int lrow = lane & 15, quad = lane >> 4;
  const int id = blockIdx.x;
  const int rk0 = id >> 5, bh = id & 31;
  const int t = c_rt[rk0], part = c_rp[rk0];
  const int b = bh >> 4, h = bh & 15;
  const int kbeg = (part == 1) ? (t + 1) : 0;          // 64-key tile units
  const int kend = (part == 0) ? (t + 1) : (2 * t + 2);

  const u16* qp = qb + (size_t)bh * SEQ * HD;
  const u16* kp = kb + (size_t)bh * SEQ * HD;
  const u16* vp = vtb + (size_t)bh * HD * SEQ;

  const int qa = t * 128 + wave * 32 + lrow;    // q-group a
  const int qg2 = qa + 16;                      // q-group b
  bf16x8 bqa[2], bqb[2];
#pragma unroll
  for (int hc = 0; hc < 2; ++hc) {
    bqa[hc] = *(const bf16x8*)(qp + (size_t)qa * HD + hc * 32 + quad * 8);
    bqb[hc] = *(const bf16x8*)(qp + (size_t)qg2 * HD + hc * 32 + quad * 8);
  }

  const int sw = lrow & 7;
  const bf16x4 ones = {(short)0x3F80, (short)0x3F80, (short)0x3F80, (short)0x3F80};

  // stage 64-key K/V tile kt into buffer buf (8 KB each, 2 rounds of 256x16B)
#define STAGE_KV(kt, buf)                                                          \
  {                                                                                \
    int _kt = (kt);                                                                \
    _Pragma("unroll")                                                              \
    for (int it = 0; it < 2; ++it) {                                               \
      int f = it * 256 + tid;                                                      \
      int rr = f >> 3, cc = f & 7;                                                 \
      gload16(kp + (size_t)(_kt * 64 + rr) * HD + ((cc ^ (rr & 7)) << 3),          \
              Ks[buf] + f * 8);                                                    \
      gload16(vp + (size_t)rr * SEQ + _kt * 64 + ((cc ^ (rr & 7)) << 3),           \
              Vts[buf] + f * 8);                                                   \
    }                                                                              \
  }

  STAGE_KV(kbeg, 0);

  f32x4 oa[4] = {}, ob[4] = {};
  f32x4 lca = {}, lcb = {};

  for (int kt = kbeg; kt < kend; ++kt) {
    const int cur = (kt - kbeg) & 1, nxt = cur ^ 1;
    __syncthreads();                   // drains cur staging; guards LDS reuse
    if (kt + 1 < kend) STAGE_KV(kt + 1, nxt);

    // S^T = K.Q^T, C-init = -12 (exp2 offset). Shared ak feeds both q-groups.
    f32x4 sa[4], sb[4];
#pragma unroll
    for (int ki = 0; ki < 4; ++ki) { sa[ki] = -12.f; sb[ki] = -12.f; }
#pragma unroll
    for (int hc = 0; hc < 2; ++hc) {
      bf16x8 ak[4];
#pragma unroll
      for (int ki = 0; ki < 4; ++ki)
        ak[ki] = *(const bf16x8*)(Ks[cur] + (ki * 16 + lrow) * 64 +
                                  (((hc * 4 + quad) ^ sw) << 3));
#pragma unroll
      for (int ki = 0; ki < 4; ++ki)
        sa[ki] = __builtin_amdgcn_mfma_f32_16x16x32_bf16(ak[ki], bqa[hc], sa[ki], 0, 0, 0);
#pragma unroll
      for (int ki = 0; ki < 4; ++ki)
        sb[ki] = __builtin_amdgcn_mfma_f32_16x16x32_bf16(ak[ki], bqb[hc], sb[ki], 0, 0, 0);
    }

    if (kt >= 2 * t) {                 // diagonal zone (last two 64-key tiles)
#pragma unroll
      for (int ki = 0; ki < 4; ++ki)
#pragma unroll
        for (int r = 0; r < 4; ++r) {
          int key = kt * 64 + ki * 16 + quad * 4 + r;
          if (key > qa)  sa[ki][r] = -1e30f;
          if (key > qg2) sb[ki][r] = -1e30f;
        }
    }

    // exp2 (offset already applied) + packed P fragments
    bf16x4 pfa[4], pfb[4];
#pragma unroll
    for (int ki = 0; ki < 4; ++ki) {
#pragma unroll
      for (int r = 0; r < 4; ++r) { sa[ki][r] = exp2f(sa[ki][r]); sb[ki][r] = exp2f(sb[ki][r]); }
      pfa[ki] = pack4(sa[ki][0], sa[ki][1], sa[ki][2], sa[ki][3]);
      pfb[ki] = pack4(sb[ki][0], sb[ki][1], sb[ki][2], sb[ki][3]);
    }

    // O^T += V^T.P^T — shared av feeds both q-groups
#pragma unroll
    for (int mi = 0; mi < 4; ++mi) {
      int vrow = (mi * 16 + lrow) * 64;
#pragma unroll
      for (int ki = 0; ki < 4; ++ki) {
        bf16x4 av = *(const bf16x4*)(Vts[cur] + vrow +
                                     ((((ki * 2 + (quad >> 1)) ^ sw) << 3) | ((quad & 1) << 2)));
        oa[mi] = mfma16(av, pfa[ki], oa[mi]);
        ob[mi] = mfma16(av, pfb[ki], ob[mi]);
      }
    }
    // denominator on the MFMA pipe: every C row = sum_k P[k][q]
#pragma unroll
    for (int ki = 0; ki < 4; ++ki) {
      lca = mfma16(ones, pfa[ki], lca);
      lcb = mfma16(ones, pfb[ki], lcb);
    }
  }

  const float l_a = lca[0], l_b = lcb[0];   // broadcast across regs & quads

  if (part == 2) {
    float ra = 1.f / l_a, rb = 1.f / l_b;
    u16* opa = attnb + ((size_t)(b * SEQ + qa)) * D_MODEL + h * HD;
    u16* opb = attnb + ((size_t)(b * SEQ + qg2)) * D_MODEL + h * HD;
#pragma unroll
    for (int mi = 0; mi < 4; ++mi) {
      ushort4 pka = packu4(oa[mi][0] * ra, oa[mi][1] * ra, oa[mi][2] * ra, oa[mi][3] * ra);
      *(ushort4*)(opa + mi * 16 + quad * 4) = pka;
      ushort4 pkb = packu4(ob[mi][0] * rb, ob[mi][1] * rb, ob[mi][2] * rb, ob[mi][3] * rb);
      *(ushort4*)(opb + mi * 16 + quad * 4) = pkb;
    }
  } else {
    // split block: un-normalized partials. unit u in [0,224), partner at +224.
    const int u = (t - 9) * 32 + bh;
    const int slot = part * 224 + u;
    u16* poa = opart + ((size_t)slot * 128 + wave * 32 + lrow) * 64;
    u16* pob = poa + (size_t)16 * 64;
#pragma unroll
    for (int mi = 0; mi < 4; ++mi) {
      ushort4 pka = packu4(oa[mi][0], oa[mi][1], oa[mi][2], oa[mi][3]);
      *(ushort4*)(poa + mi * 16 + quad * 4) = pka;
      ushort4 pkb = packu4(ob[mi][0], ob[mi][1], ob[mi][2], ob[mi][3]);
      *(ushort4*)(pob + mi * 16 + quad * 4) = pkb;
    }
    if (quad == 0) {
      lpart[slot * 128 + wave * 32 + lrow] = l_a;
      lpart[slot * 128 + wave * 32 + lrow + 16] = l_b;
    }
  }
#undef STAGE_KV
}

// ---- combine split partials: O = (p0+p1)/(l0+l1) -> attnb bf16 ----
__global__ void combine_kernel(const u16* __restrict__ opart, const float* __restrict__ lpart,
                               u16* __restrict__ attnb) {
  int gid = blockIdx.x * 256 + threadIdx.x;   // 224*128*16 = 458752
  int lane16 = gid & 15, row = gid >> 4;      // row in [0, 28672)
  int u = row >> 7, trow = row & 127;
  int t = 9 + (u >> 5), bh = u & 31;
  const u16* p0 = opart + ((size_t)u * 128 + trow) * 64 + lane16 * 4;
  const u16* p1 = opart + ((size_t)(224 + u) * 128 + trow) * 64 + lane16 * 4;
  float rl = 1.f / (lpart[u * 128 + trow] + lpart[(224 + u) * 128 + trow]);
  ushort4 a = *(const ushort4*)p0;
  ushort4 c = *(const ushort4*)p1;
  ushort4 o = packu4((bf2f(a.x) + bf2f(c.x)) * rl, (bf2f(a.y) + bf2f(c.y)) * rl,
                     (bf2f(a.z) + bf2f(c.z)) * rl, (bf2f(a.w) + bf2f(c.w)) * rl);
  int b = bh >> 4, h = bh & 15, qrow = t * 128 + trow;
  *(ushort4*)(attnb + ((size_t)(b * SEQ + qrow)) * D_MODEL + h * HD + lane16 * 4) = o;
}

// -------- output projection: 128x64 tiles, swapped operands -> float4 stores ----
__global__ __launch_bounds__(256) void out_gemm_kernel(
    const u16* __restrict__ A, const u16* __restrict__ Bt, const float* __restrict__ bias,
    float* __restrict__ out) {
  __shared__ u16 As[128 * 64];
  __shared__ u16 Bs[64 * 64];
  const int tid = threadIdx.x;
  const int lane = tid & 63, wave = tid >> 6;
  const int lrow = lane & 15, quad = lane >> 4;
  const int sw = lrow & 7;
  const int wr = wave * 32;
  const int rowA0 = blockIdx.y * 128, colB0 = blockIdx.x * 64;

  f32x4 acc[2][4] = {};

  for (int k0 = 0; k0 < KDIM; k0 += 64) {
    __syncthreads();
#pragma unroll
    for (int it = 0; it < 4; ++it) {
      int f = it * 256 + tid;
      int r = f >> 3, cs = ((f & 7) ^ (r & 7)) << 3;
      gload16(A + (size_t)(rowA0 + r) * KDIM + k0 + cs, As + f * 8);
    }
#pragma unroll
    for (int it = 0; it < 2; ++it) {
      int f = it * 256 + tid;
      int r = f >> 3, cs = ((f & 7) ^ (r & 7)) << 3;
      gload16(Bt + (size_t)(colB0 + r) * KDIM + k0 + cs, Bs + f * 8);
    }
    __syncthreads();
#pragma unroll
    for (int kk = 0; kk < 64; kk += 32) {
      const int ch = ((kk >> 3) + quad) ^ sw;
      bf16x8 af[2], bfr[4];
#pragma unroll
      for (int mi = 0; mi < 2; ++mi)
        af[mi] = *(const bf16x8*)(As + (wr + mi * 16 + lrow) * 64 + (ch << 3));
#pragma unroll
      for (int ni = 0; ni < 4; ++ni)
        bfr[ni] = *(const bf16x8*)(Bs + (ni * 16 + lrow) * 64 + (ch << 3));
      // swapped operands: lane&15 <-> A-row (s), quad*4+r <-> B-row (col)
#pragma unroll
      for (int mi = 0; mi < 2; ++mi)
#pragma unroll
        for (int ni = 0; ni < 4; ++ni)
          acc[mi][ni] = __builtin_amdgcn_mfma_f32_16x16x32_bf16(bfr[ni], af[mi], acc[mi][ni], 0, 0, 0);
    }
  }

#pragma unroll
  for (int ni = 0; ni < 4; ++ni) {
    float4 bv = *(const float4*)&bias[colB0 + ni * 16 + quad * 4];
#pragma unroll
    for (int mi = 0; mi < 2; ++mi) {
      int row = rowA0 + wr + mi * 16 + lrow;
      float4 o4 = make_float4(acc[mi][ni][0] + bv.x, acc[mi][ni][1] + bv.y,
                              acc[mi][ni][2] + bv.z, acc[mi][ni][3] + bv.w);
      *(float4*)&out[(size_t)row * D_MODEL + colB0 + ni * 16 + quad * 4] = o4;
    }
  }
}

extern "C" void kernel_launch(void* const* d_in, const int* in_sizes, int n_in,
                              void* d_out, int out_size, void* d_ws, size_t ws_size,
                              hipStream_t stream) {
  const float* query = (const float*)d_in[0];
  const float* W_qkv = (const float*)d_in[1];
  const float* b_qkv = (const float*)d_in[2];
  const float* W_out = (const float*)d_in[3];
  const float* b_out = (const float*)d_in[4];
  float* out = (float*)d_out;

  char* ws = (char*)d_ws;
  u16* q_bf    = (u16*)(ws);                 //  8 MB  query bf16 (dead after qkv)
  u16* wt_qkv  = (u16*)(ws + 8388608);       //  6 MB  W_qkv^T bf16 (dead after qkv)
  u16* wt_out  = (u16*)(ws + 14680064);      //  2 MB  W_out^T bf16
  u16* qbuf    = (u16*)(ws + 16777216);      //  8 MB  q (bh,s,hd) plain, pre-scaled kS
  u16* kbuf    = (u16*)(ws + 25165824);      //  8 MB  k (bh,s,hd) plain
  u16* vtbuf   = (u16*)(ws + 33554432);      //  8 MB  v^T (bh,hd,s) plain
  u16* attnb   = (u16*)(ws + 41943040);      //  8 MB  attn (B,S,D) bf16
  float2* rope = (float2*)(ws + 50331648);   // 512 KB rope table [s][f]
  // flash split-K partials ALIAS the dead q_bf region (flash runs after qkv):
  u16* opart   = (u16*)(ws);                 // 448 units x 128x64 bf16 = 7.34 MB
  float* lpart = (float*)(ws + 7340032);     // 448 x 128 fp32 = 229 KB (< 8 MB ✓)

  prep_kernel<<<dim3(8448), dim3(256), 0, stream>>>(query, q_bf, W_qkv, wt_qkv,
                                                    W_out, wt_out, rope);
  qkv_gemm_kernel<<<dim3(NQKV / 128, ROWS / 128), dim3(256), 0, stream>>>(
      q_bf, wt_qkv, b_qkv, rope, qbuf, kbuf, vtbuf);
  flash_kernel<<<dim3(736), dim3(256), 0, stream>>>(qbuf, kbuf, vtbuf, attnb, opart, lpart);
  combine_kernel<<<dim3(1792), dim3(256), 0, stream>>>(opart, lpart, attnb);
  out_gemm_kernel<<<dim3(D_MODEL / 64, ROWS / 128), dim3(256), 0, stream>>>(
      attnb, wt_out, b_out, out);
}